// Round 15
// baseline (919.653 us; speedup 1.0000x reference)
//
#include <hip/hip_runtime.h>
#include <hip/hip_bf16.h>
#include <stdint.h>

#define N_NODES 50000
#define E_EDGES 800000

typedef short s16x8 __attribute__((ext_vector_type(8)));
typedef float f32x4 __attribute__((ext_vector_type(4)));

__device__ __forceinline__ float bf2f(unsigned int u) {
    return __uint_as_float(u << 16);
}
__device__ __forceinline__ unsigned short f2bf(float f) {
    unsigned int u = __float_as_uint(f);
    unsigned int r = (u + 0x7FFFu + ((u >> 16) & 1u)) >> 16;
    return (unsigned short)r;
}
__device__ __forceinline__ void split_bf(float v, unsigned short& hi, unsigned short& lo) {
    hi = f2bf(v);
    lo = f2bf(v - bf2f(hi));
}
#define MFMA(a, b, c) __builtin_amdgcn_mfma_f32_16x16x32_bf16((a), (b), (c), 0, 0, 0)

// ---------------- CSR construction (R11) ----------------

__global__ void hist_deg(const int* __restrict__ dst, int* __restrict__ deg) {
    int e = blockIdx.x * blockDim.x + threadIdx.x;
    if (e >= E_EDGES) return;
    atomicAdd(&deg[dst[e]], 1);
}

__global__ __launch_bounds__(1024) void scan1(const int* __restrict__ deg,
                                              int* __restrict__ lexcl,
                                              int* __restrict__ btot) {
    __shared__ int wsum[16];
    int gid = blockIdx.x * 1024 + threadIdx.x;
    int lane = threadIdx.x & 63, wid = threadIdx.x >> 6;
    int v = (gid < N_NODES) ? deg[gid] : 0;
    int x = v;
#pragma unroll
    for (int off = 1; off < 64; off <<= 1) {
        int t = __shfl_up(x, off);
        if (lane >= off) x += t;
    }
    if (lane == 63) wsum[wid] = x;
    __syncthreads();
    if (wid == 0 && lane < 16) {
        int w = wsum[lane];
#pragma unroll
        for (int off = 1; off < 16; off <<= 1) {
            int t = __shfl_up(w, off);
            if (lane >= off) w += t;
        }
        wsum[lane] = w;
    }
    __syncthreads();
    int excl = x - v + (wid ? wsum[wid - 1] : 0);
    if (gid < N_NODES) lexcl[gid] = excl;
    if (threadIdx.x == 0) btot[blockIdx.x] = wsum[15];
}

__global__ void scan2(const int* __restrict__ btot, int* __restrict__ bbase,
                      int nb) {
    int lane = threadIdx.x;
    int v = (lane < nb) ? btot[lane] : 0;
    int x = v;
#pragma unroll
    for (int off = 1; off < 64; off <<= 1) {
        int t = __shfl_up(x, off);
        if (lane >= off) x += t;
    }
    if (lane < nb) bbase[lane] = x - v;
}

__global__ void scan3(const int* __restrict__ lexcl, const int* __restrict__ bbase,
                      int* __restrict__ rowptr, int* __restrict__ cursor) {
    int gid = blockIdx.x * blockDim.x + threadIdx.x;
    if (gid < N_NODES) {
        int r = lexcl[gid] + bbase[gid >> 10];
        rowptr[gid] = r;
        cursor[gid] = r;
    }
    if (gid == 0) rowptr[N_NODES] = E_EDGES;
}

__global__ void fill_csr(const int* __restrict__ src, const int* __restrict__ dst,
                         int* __restrict__ cursor, unsigned short* __restrict__ perm) {
    int e = blockIdx.x * blockDim.x + threadIdx.x;
    if (e >= E_EDGES) return;
    int d = dst[e];
    int pos = atomicAdd(&cursor[d], 1);
    perm[pos] = (unsigned short)src[e];
}

// ---------------- Aggregation (R5/R11 shape — best measured, at issue-limit) ----
__global__ __launch_bounds__(256) void gather_agg(
    const float* __restrict__ feat,
    const int* __restrict__ rowptr,
    const unsigned short* __restrict__ perm,
    float* __restrict__ out) {
    int node = (blockIdx.x * 256 + threadIdx.x) >> 6;
    if (node >= N_NODES) return;
    int lane = threadIdx.x & 63;
    const float2* fv = (const float2*)feat;
    float2 acc = fv[(size_t)node * 64 + lane];
    int beg = rowptr[node], end = rowptr[node + 1];
    for (int base = beg; base < end; base += 64) {
        int cnt = end - base; if (cnt > 64) cnt = 64;
        int pv = (base + lane < end) ? (int)perm[base + lane] : 0;
        int j = 0;
        for (; j + 1 < cnt; j += 2) {
            int s0 = __shfl(pv, j);
            int s1 = __shfl(pv, j + 1);
            float2 v0 = fv[(size_t)s0 * 64 + lane];
            float2 v1 = fv[(size_t)s1 * 64 + lane];
            acc.x += v0.x + v1.x;
            acc.y += v0.y + v1.y;
        }
        if (j < cnt) {
            int s = __shfl(pv, j);
            float2 v = fv[(size_t)s * 64 + lane];
            acc.x += v.x;
            acc.y += v.y;
        }
    }
    ((float2*)out)[(size_t)node * 64 + lane] = acc;
}

// ---- Weight pre-split (fused) ----
__device__ __forceinline__ void prep_one(const float* __restrict__ W,
                                         unsigned short* __restrict__ Whi,
                                         unsigned short* __restrict__ Wlo,
                                         int K, int F, int Fpad, int i) {
    int S = K / 32, T = Fpad / 16;
    int total = T * S * 64;
    if (i >= total) return;
    int lane = i & 63;
    int s = (i >> 6) % S;
    int t = (i >> 6) / S;
    int col = t * 16 + (lane & 15);
    int k0 = s * 32 + (lane >> 4) * 8;
    s16x8 vh, vl;
#pragma unroll
    for (int j = 0; j < 8; j++) {
        float w = (col < F) ? W[(size_t)(k0 + j) * F + col] : 0.f;
        unsigned short h, l;
        split_bf(w, h, l);
        vh[j] = (short)h;
        vl[j] = (short)l;
    }
    *(s16x8*)(Whi + (size_t)i * 8) = vh;
    *(s16x8*)(Wlo + (size_t)i * 8) = vl;
}

__global__ void prep_all(const float* W1, const float* W2, const float* W3,
                         const float* W4, const float* Wl,
                         unsigned short* W1h, unsigned short* W1l,
                         unsigned short* W2h, unsigned short* W2l,
                         unsigned short* W3h, unsigned short* W3l,
                         unsigned short* W4h, unsigned short* W4l,
                         unsigned short* Wlh, unsigned short* Wll) {
    int b = blockIdx.x, t = threadIdx.x;
    if (b < 8)       prep_one(W1, W1h, W1l, 128, 128, 128, b * 256 + t);
    else if (b < 16) prep_one(W2, W2h, W2l, 128, 128, 128, (b - 8) * 256 + t);
    else if (b < 32) prep_one(W3, W3h, W3l, 128, 256, 256, (b - 16) * 256 + t);
    else if (b < 64) prep_one(W4, W4h, W4l, 256, 256, 256, (b - 32) * 256 + t);
    else             prep_one(Wl, Wlh, Wll, 256, 40, 48, (b - 64) * 256 + t);
}

// ---- GEMM, split-precision bf16 MFMA, R11 config + LDS-staged B-fragments.
// B-frags loaded once per BLOCK (not per wave): 4x less global B traffic on the
// TA/L1 issue path; waves re-read from LDS (separate DS pipe). Double-buffered:
// prefetch loads issued before compute, ds_write after compute, 1 barrier/chunk.
template <int K, int F, int FOUT, bool RELU, int CSPLIT, int RPW>
__global__ __launch_bounds__(256) void gemm_lds(
    const float* __restrict__ A,
    const unsigned short* __restrict__ Whi,
    const unsigned short* __restrict__ Wlo,
    const float* __restrict__ bias,
    float* __restrict__ out) {
    constexpr int S = K / 32;
    constexpr int T = F / 16;
    constexpr int TL = T / CSPLIT;
    constexpr int NF = 2 * TL;            // fragments per k-chunk (hi+lo)
    constexpr int NPW = (NF + 3) / 4;     // fragments staged per wave
    __shared__ __align__(16) unsigned short Bs[2][NF][64][8];

    int half = blockIdx.x % CSPLIT;
    int rc   = blockIdx.x / CSPLIT;
    int wave = threadIdx.x >> 6;
    int lane = threadIdx.x & 63;
    int row0 = rc * (64 * RPW) + wave * (16 * RPW);
    bool wvalid = row0 < N_NODES;         // NO early return: all waves hit barriers
    int row0L = wvalid ? row0 : 0;
    int lm = lane & 15;
    int quad = lane >> 4;
    bool rv[RPW];
#pragma unroll
    for (int r = 0; r < RPW; r++) rv[r] = wvalid && (row0 + r * 16) < N_NODES;

    f32x4 acc[TL][RPW];
#pragma unroll
    for (int t = 0; t < TL; t++)
#pragma unroll
        for (int r = 0; r < RPW; r++) {
            f32x4 z = {0.f, 0.f, 0.f, 0.f};
            acc[t][r] = z;
        }

    // ---- stage s=0 into buffer 0 ----
    {
        s16x8 v[NPW];
        int i = 0;
#pragma unroll
        for (int f = 0; f < NF; f++) {
            if ((f & 3) != wave) continue;
            const unsigned short* W = (f & 1) ? Wlo : Whi;
            int tg = half * TL + (f >> 1);
            v[i++] = *(const s16x8*)(W + ((size_t)(tg * S + 0) * 64 + lane) * 8);
        }
        i = 0;
#pragma unroll
        for (int f = 0; f < NF; f++) {
            if ((f & 3) != wave) continue;
            *(s16x8*)&Bs[0][f][lane][0] = v[i++];
        }
    }
    __syncthreads();

#pragma unroll
    for (int s = 0; s < S; s++) {
        // issue prefetch loads for s+1 (no use until after compute)
        s16x8 pf[NPW];
        if (s + 1 < S) {
            int i = 0;
#pragma unroll
            for (int f = 0; f < NF; f++) {
                if ((f & 3) != wave) continue;
                const unsigned short* W = (f & 1) ? Wlo : Whi;
                int tg = half * TL + (f >> 1);
                pf[i++] = *(const s16x8*)(W + ((size_t)(tg * S + s + 1) * 64 + lane) * 8);
            }
        }

        // A loads + split (R11 path)
        s16x8 ah[RPW], al[RPW];
#pragma unroll
        for (int r = 0; r < RPW; r++) {
            int rr = rv[r] ? row0 + r * 16 : row0L;
            const float* ap = A + (size_t)(rr + lm) * K + s * 32 + quad * 8;
            float4 x0 = *(const float4*)ap;
            float4 x1 = *(const float4*)(ap + 4);
            float v[8] = {x0.x, x0.y, x0.z, x0.w, x1.x, x1.y, x1.z, x1.w};
#pragma unroll
            for (int j = 0; j < 8; j++) {
                unsigned short h, l;
                split_bf(v[j], h, l);
                ah[r][j] = (short)h;
                al[r][j] = (short)l;
            }
        }

        // MFMAs reading B-frags from LDS (conflict-free ds_read_b128)
#pragma unroll
        for (int t = 0; t < TL; t++) {
            const s16x8 bh = *(const s16x8*)&Bs[s & 1][2 * t][lane][0];
            const s16x8 bl = *(const s16x8*)&Bs[s & 1][2 * t + 1][lane][0];
#pragma unroll
            for (int r = 0; r < RPW; r++) {
                acc[t][r] = MFMA(ah[r], bh, acc[t][r]);
                acc[t][r] = MFMA(al[r], bh, acc[t][r]);
                acc[t][r] = MFMA(ah[r], bl, acc[t][r]);
            }
        }

        // write prefetched frags to the other buffer, then barrier
        if (s + 1 < S) {
            int i = 0;
#pragma unroll
            for (int f = 0; f < NF; f++) {
                if ((f & 3) != wave) continue;
                *(s16x8*)&Bs[(s + 1) & 1][f][lane][0] = pf[i++];
            }
        }
        __syncthreads();
    }

#pragma unroll
    for (int r = 0; r < RPW; r++) {
        if (!rv[r]) break;
        int orow = row0 + r * 16 + quad * 4;
#pragma unroll
        for (int t = 0; t < TL; t++) {
            int col = (half * TL + t) * 16 + lm;
            if (FOUT < F && col >= FOUT) continue;
            float bv = bias[col];
#pragma unroll
            for (int q = 0; q < 4; q++) {
                float vv = acc[t][r][q] + bv;
                if (RELU) vv = fmaxf(vv, 0.f);
                out[(size_t)(orow + q) * FOUT + col] = vv;
            }
        }
    }
}

extern "C" void kernel_launch(void* const* d_in, const int* in_sizes, int n_in,
                              void* d_out, int out_size, void* d_ws, size_t ws_size,
                              hipStream_t stream) {
    const float* x  = (const float*)d_in[0];
    const int* ei   = (const int*)d_in[1];
    const float* W1 = (const float*)d_in[2];
    const float* b1 = (const float*)d_in[3];
    const float* W2 = (const float*)d_in[4];
    const float* b2 = (const float*)d_in[5];
    const float* W3 = (const float*)d_in[6];
    const float* b3 = (const float*)d_in[7];
    const float* W4 = (const float*)d_in[8];
    const float* b4 = (const float*)d_in[9];
    const float* Wl = (const float*)d_in[10];
    const float* bl = (const float*)d_in[11];
    float* out = (float*)d_out;

    const int* src = ei;
    const int* dst = ei + E_EDGES;

    char* ws = (char*)d_ws;
    const size_t R = (size_t)N_NODES * 256 * 4;        // 51.2e6 B
    float* R1 = (float*)ws;
    float* R2 = (float*)(ws + R);
    float* hF  = R1;                          // [N,128] agg (layer 1 & 2)
    float* h1  = R2;                          // [N,128]
    float* h1b = R2 + (size_t)N_NODES * 128;  // [N,128]
    float* hF2 = R1;
    float* h2  = R2;                          // [N,256]
    float* h2b = R1;                          // [N,256]
    size_t off = 2 * R;
    unsigned short* W1h = (unsigned short*)(ws + off); off += 16384 * 2;
    unsigned short* W1l = (unsigned short*)(ws + off); off += 16384 * 2;
    unsigned short* W2h = (unsigned short*)(ws + off); off += 16384 * 2;
    unsigned short* W2l = (unsigned short*)(ws + off); off += 16384 * 2;
    unsigned short* W3h = (unsigned short*)(ws + off); off += 32768 * 2;
    unsigned short* W3l = (unsigned short*)(ws + off); off += 32768 * 2;
    unsigned short* W4h = (unsigned short*)(ws + off); off += 65536 * 2;
    unsigned short* W4l = (unsigned short*)(ws + off); off += 65536 * 2;
    unsigned short* Wlh = (unsigned short*)(ws + off); off += 12288 * 2;
    unsigned short* Wll = (unsigned short*)(ws + off); off += 12288 * 2;
    off = (off + 255) & ~(size_t)255;
    int* deg    = (int*)(ws + off); off += (size_t)(N_NODES + 1) * 4;
    int* cursor = (int*)(ws + off); off += (size_t)(N_NODES + 1) * 4;
    int* rowptr = (int*)(ws + off); off += (size_t)(N_NODES + 1) * 4;
    unsigned short* perm = (unsigned short*)(ws + off); off += (size_t)E_EDGES * 2;
    off = (off + 255) & ~(size_t)255;
    int* lexcl  = (int*)(ws + off); off += (size_t)N_NODES * 4;
    int* btot   = (int*)(ws + off); off += 64 * 4;
    int* bbase  = (int*)(ws + off); off += 64 * 4;
    (void)ws_size; (void)in_sizes; (void)n_in; (void)out_size;

    const int NB = (N_NODES + 1023) / 1024;

    // ---- CSR build ----
    (void)hipMemsetAsync(deg, 0, (size_t)(N_NODES + 1) * 4, stream);
    hist_deg<<<(E_EDGES + 255) / 256, 256, 0, stream>>>(dst, deg);
    scan1<<<NB, 1024, 0, stream>>>(deg, lexcl, btot);
    scan2<<<1, 64, 0, stream>>>(btot, bbase, NB);
    scan3<<<(N_NODES + 255) / 256, 256, 0, stream>>>(lexcl, bbase, rowptr, cursor);
    fill_csr<<<(E_EDGES + 255) / 256, 256, 0, stream>>>(src, dst, cursor, perm);

    // ---- Weight pre-split ----
    prep_all<<<70, 256, 0, stream>>>(W1, W2, W3, W4, Wl,
                                     W1h, W1l, W2h, W2l, W3h, W3l,
                                     W4h, W4l, Wlh, Wll);

    const int aggBlocks = (N_NODES * 64 + 255) / 256;   // one wave per node
    const int rc2 = (N_NODES + 127) / 128;              // 391 (RPW=2)
    const int rc1 = (N_NODES + 63) / 64;                // 782 (RPW=1)

    // ---- Layer 1 ----
    gather_agg<<<aggBlocks, 256, 0, stream>>>(x, rowptr, perm, hF);
    gemm_lds<128, 128, 128, true, 2, 2><<<rc2 * 2, 256, 0, stream>>>(hF, W1h, W1l, b1, h1);
    gemm_lds<128, 128, 128, true, 2, 2><<<rc2 * 2, 256, 0, stream>>>(h1, W2h, W2l, b2, h1b);

    // ---- Layer 2 ----
    gather_agg<<<aggBlocks, 256, 0, stream>>>(h1b, rowptr, perm, hF2);
    gemm_lds<128, 256, 256, true, 2, 2><<<rc2 * 2, 256, 0, stream>>>(hF2, W3h, W3l, b3, h2);
    gemm_lds<256, 256, 256, true, 2, 2><<<rc2 * 2, 256, 0, stream>>>(h2, W4h, W4l, b4, h2b);

    // ---- Final linear ----
    gemm_lds<256, 48, 40, false, 1, 1><<<rc1, 256, 0, stream>>>(h2b, Wlh, Wll, bl, out);
}

// Round 16
// 414.400 us; speedup vs baseline: 2.2192x; 2.2192x over previous
//
#include <hip/hip_runtime.h>
#include <hip/hip_bf16.h>
#include <stdint.h>

#define N_NODES 50000
#define E_EDGES 800000

typedef short s16x8 __attribute__((ext_vector_type(8)));
typedef float f32x4 __attribute__((ext_vector_type(4)));

__device__ __forceinline__ float bf2f(unsigned int u) {
    return __uint_as_float(u << 16);
}
__device__ __forceinline__ unsigned short f2bf(float f) {
    unsigned int u = __float_as_uint(f);
    unsigned int r = (u + 0x7FFFu + ((u >> 16) & 1u)) >> 16;
    return (unsigned short)r;
}

// ---------------- CSR construction (R11) ----------------

__global__ void hist_deg(const int* __restrict__ dst, int* __restrict__ deg) {
    int e = blockIdx.x * blockDim.x + threadIdx.x;
    if (e >= E_EDGES) return;
    atomicAdd(&deg[dst[e]], 1);
}

__global__ __launch_bounds__(1024) void scan1(const int* __restrict__ deg,
                                              int* __restrict__ lexcl,
                                              int* __restrict__ btot) {
    __shared__ int wsum[16];
    int gid = blockIdx.x * 1024 + threadIdx.x;
    int lane = threadIdx.x & 63, wid = threadIdx.x >> 6;
    int v = (gid < N_NODES) ? deg[gid] : 0;
    int x = v;
#pragma unroll
    for (int off = 1; off < 64; off <<= 1) {
        int t = __shfl_up(x, off);
        if (lane >= off) x += t;
    }
    if (lane == 63) wsum[wid] = x;
    __syncthreads();
    if (wid == 0 && lane < 16) {
        int w = wsum[lane];
#pragma unroll
        for (int off = 1; off < 16; off <<= 1) {
            int t = __shfl_up(w, off);
            if (lane >= off) w += t;
        }
        wsum[lane] = w;
    }
    __syncthreads();
    int excl = x - v + (wid ? wsum[wid - 1] : 0);
    if (gid < N_NODES) lexcl[gid] = excl;
    if (threadIdx.x == 0) btot[blockIdx.x] = wsum[15];
}

__global__ void scan2(const int* __restrict__ btot, int* __restrict__ bbase,
                      int nb) {
    int lane = threadIdx.x;
    int v = (lane < nb) ? btot[lane] : 0;
    int x = v;
#pragma unroll
    for (int off = 1; off < 64; off <<= 1) {
        int t = __shfl_up(x, off);
        if (lane >= off) x += t;
    }
    if (lane < nb) bbase[lane] = x - v;
}

__global__ void scan3(const int* __restrict__ lexcl, const int* __restrict__ bbase,
                      int* __restrict__ rowptr, int* __restrict__ cursor) {
    int gid = blockIdx.x * blockDim.x + threadIdx.x;
    if (gid < N_NODES) {
        int r = lexcl[gid] + bbase[gid >> 10];
        rowptr[gid] = r;
        cursor[gid] = r;
    }
    if (gid == 0) rowptr[N_NODES] = E_EDGES;
}

__global__ void fill_csr(const int* __restrict__ src, const int* __restrict__ dst,
                         int* __restrict__ cursor, unsigned short* __restrict__ perm) {
    int e = blockIdx.x * blockDim.x + threadIdx.x;
    if (e >= E_EDGES) return;
    int d = dst[e];
    int pos = atomicAdd(&cursor[d], 1);
    perm[pos] = (unsigned short)src[e];
}

// ---------------- Aggregation (R5/R11 shape — best measured) ----------------
__global__ __launch_bounds__(256) void gather_agg(
    const float* __restrict__ feat,
    const int* __restrict__ rowptr,
    const unsigned short* __restrict__ perm,
    float* __restrict__ out) {
    int node = (blockIdx.x * 256 + threadIdx.x) >> 6;
    if (node >= N_NODES) return;
    int lane = threadIdx.x & 63;
    const float2* fv = (const float2*)feat;
    float2 acc = fv[(size_t)node * 64 + lane];
    int beg = rowptr[node], end = rowptr[node + 1];
    for (int base = beg; base < end; base += 64) {
        int cnt = end - base; if (cnt > 64) cnt = 64;
        int pv = (base + lane < end) ? (int)perm[base + lane] : 0;
        int j = 0;
        for (; j + 1 < cnt; j += 2) {
            int s0 = __shfl(pv, j);
            int s1 = __shfl(pv, j + 1);
            float2 v0 = fv[(size_t)s0 * 64 + lane];
            float2 v1 = fv[(size_t)s1 * 64 + lane];
            acc.x += v0.x + v1.x;
            acc.y += v0.y + v1.y;
        }
        if (j < cnt) {
            int s = __shfl(pv, j);
            float2 v = fv[(size_t)s * 64 + lane];
            acc.x += v.x;
            acc.y += v.y;
        }
    }
    ((float2*)out)[(size_t)node * 64 + lane] = acc;
}

// ---- Weight pre-split (fused) ----
__device__ __forceinline__ void prep_one(const float* __restrict__ W,
                                         unsigned short* __restrict__ Whi,
                                         unsigned short* __restrict__ Wlo,
                                         int K, int F, int Fpad, int i) {
    int S = K / 32, T = Fpad / 16;
    int total = T * S * 64;
    if (i >= total) return;
    int lane = i & 63;
    int s = (i >> 6) % S;
    int t = (i >> 6) / S;
    int col = t * 16 + (lane & 15);
    int k0 = s * 32 + (lane >> 4) * 8;
    s16x8 vh, vl;
#pragma unroll
    for (int j = 0; j < 8; j++) {
        float w = (col < F) ? W[(size_t)(k0 + j) * F + col] : 0.f;
        unsigned short h = f2bf(w);
        float r = w - bf2f(h);
        vh[j] = (short)h;
        vl[j] = (short)f2bf(r);
    }
    *(s16x8*)(Whi + (size_t)i * 8) = vh;
    *(s16x8*)(Wlo + (size_t)i * 8) = vl;
}

__global__ void prep_all(const float* W1, const float* W2, const float* W3,
                         const float* W4, const float* Wl,
                         unsigned short* W1h, unsigned short* W1l,
                         unsigned short* W2h, unsigned short* W2l,
                         unsigned short* W3h, unsigned short* W3l,
                         unsigned short* W4h, unsigned short* W4l,
                         unsigned short* Wlh, unsigned short* Wll) {
    int b = blockIdx.x, t = threadIdx.x;
    if (b < 8)       prep_one(W1, W1h, W1l, 128, 128, 128, b * 256 + t);
    else if (b < 16) prep_one(W2, W2h, W2l, 128, 128, 128, (b - 8) * 256 + t);
    else if (b < 32) prep_one(W3, W3h, W3l, 128, 256, 256, (b - 16) * 256 + t);
    else if (b < 64) prep_one(W4, W4h, W4l, 256, 256, 256, (b - 32) * 256 + t);
    else             prep_one(Wl, Wlh, Wll, 256, 40, 48, (b - 64) * 256 + t);
}

// ---- GEMM, split-precision bf16 MFMA (R11 kernel, unchanged).
// RPW row-tiles (16 rows each) per wave, CSPLIT column chunks per grid.
template <int K, int F, int FOUT, bool RELU, int CSPLIT, int RPW>
__global__ __launch_bounds__(256) void gemm_split(
    const float* __restrict__ A,
    const unsigned short* __restrict__ Whi,
    const unsigned short* __restrict__ Wlo,
    const float* __restrict__ bias,
    float* __restrict__ out) {
    constexpr int S = K / 32;
    constexpr int T = F / 16;
    constexpr int TL = T / CSPLIT;
    int half = blockIdx.x % CSPLIT;
    int rc   = blockIdx.x / CSPLIT;
    int wave = threadIdx.x >> 6;
    int lane = threadIdx.x & 63;
    int row0 = rc * (64 * RPW) + wave * (16 * RPW);
    if (row0 >= N_NODES) return;
    int lm = lane & 15;
    int quad = lane >> 4;
    bool rv[RPW];
#pragma unroll
    for (int r = 0; r < RPW; r++) rv[r] = (row0 + r * 16) < N_NODES;

    f32x4 acc[TL][RPW];
#pragma unroll
    for (int t = 0; t < TL; t++)
#pragma unroll
        for (int r = 0; r < RPW; r++) {
            f32x4 z = {0.f, 0.f, 0.f, 0.f};
            acc[t][r] = z;
        }

#pragma unroll
    for (int s = 0; s < S; s++) {
        s16x8 ah[RPW], al[RPW];
#pragma unroll
        for (int r = 0; r < RPW; r++) {
            int rr = rv[r] ? row0 + r * 16 : row0;
            const float* ap = A + (size_t)(rr + lm) * K + s * 32 + quad * 8;
            float4 x0 = *(const float4*)ap;
            float4 x1 = *(const float4*)(ap + 4);
            float v[8] = {x0.x, x0.y, x0.z, x0.w, x1.x, x1.y, x1.z, x1.w};
#pragma unroll
            for (int j = 0; j < 8; j++) {
                unsigned short h = f2bf(v[j]);
                float res = v[j] - bf2f(h);
                ah[r][j] = (short)h;
                al[r][j] = (short)f2bf(res);
            }
        }
#pragma unroll
        for (int t = 0; t < TL; t++) {
            int tg = half * TL + t;
            const size_t fi = (size_t)((tg * S + s) * 64 + lane) * 8;
            const s16x8 bh = *(const s16x8*)(Whi + fi);
            const s16x8 bl = *(const s16x8*)(Wlo + fi);
#pragma unroll
            for (int r = 0; r < RPW; r++) {
                acc[t][r] = __builtin_amdgcn_mfma_f32_16x16x32_bf16(ah[r], bh, acc[t][r], 0, 0, 0);
                acc[t][r] = __builtin_amdgcn_mfma_f32_16x16x32_bf16(al[r], bh, acc[t][r], 0, 0, 0);
                acc[t][r] = __builtin_amdgcn_mfma_f32_16x16x32_bf16(ah[r], bl, acc[t][r], 0, 0, 0);
            }
        }
    }

#pragma unroll
    for (int r = 0; r < RPW; r++) {
        if (!rv[r]) break;
        int orow = row0 + r * 16 + quad * 4;
#pragma unroll
        for (int t = 0; t < TL; t++) {
            int col = (half * TL + t) * 16 + lm;
            if (FOUT < F && col >= FOUT) continue;
            float bv = bias[col];
#pragma unroll
            for (int q = 0; q < 4; q++) {
                float vv = acc[t][r][q] + bv;
                if (RELU) vv = fmaxf(vv, 0.f);
                out[(size_t)(orow + q) * FOUT + col] = vv;
            }
        }
    }
}

extern "C" void kernel_launch(void* const* d_in, const int* in_sizes, int n_in,
                              void* d_out, int out_size, void* d_ws, size_t ws_size,
                              hipStream_t stream) {
    const float* x  = (const float*)d_in[0];
    const int* ei   = (const int*)d_in[1];
    const float* W1 = (const float*)d_in[2];
    const float* b1 = (const float*)d_in[3];
    const float* W2 = (const float*)d_in[4];
    const float* b2 = (const float*)d_in[5];
    const float* W3 = (const float*)d_in[6];
    const float* b3 = (const float*)d_in[7];
    const float* W4 = (const float*)d_in[8];
    const float* b4 = (const float*)d_in[9];
    const float* Wl = (const float*)d_in[10];
    const float* bl = (const float*)d_in[11];
    float* out = (float*)d_out;

    const int* src = ei;
    const int* dst = ei + E_EDGES;

    char* ws = (char*)d_ws;
    const size_t R = (size_t)N_NODES * 256 * 4;        // 51.2e6 B
    float* R1 = (float*)ws;
    float* R2 = (float*)(ws + R);
    float* hF  = R1;                          // [N,128] agg (layer 1 & 2)
    float* h1  = R2;                          // [N,128]
    float* h1b = R2 + (size_t)N_NODES * 128;  // [N,128]
    float* hF2 = R1;
    float* h2  = R2;                          // [N,256]
    float* h2b = R1;                          // [N,256]
    size_t off = 2 * R;
    unsigned short* W1h = (unsigned short*)(ws + off); off += 16384 * 2;
    unsigned short* W1l = (unsigned short*)(ws + off); off += 16384 * 2;
    unsigned short* W2h = (unsigned short*)(ws + off); off += 16384 * 2;
    unsigned short* W2l = (unsigned short*)(ws + off); off += 16384 * 2;
    unsigned short* W3h = (unsigned short*)(ws + off); off += 32768 * 2;
    unsigned short* W3l = (unsigned short*)(ws + off); off += 32768 * 2;
    unsigned short* W4h = (unsigned short*)(ws + off); off += 65536 * 2;
    unsigned short* W4l = (unsigned short*)(ws + off); off += 65536 * 2;
    unsigned short* Wlh = (unsigned short*)(ws + off); off += 12288 * 2;
    unsigned short* Wll = (unsigned short*)(ws + off); off += 12288 * 2;
    off = (off + 255) & ~(size_t)255;
    int* deg    = (int*)(ws + off); off += (size_t)(N_NODES + 1) * 4;
    int* cursor = (int*)(ws + off); off += (size_t)(N_NODES + 1) * 4;
    int* rowptr = (int*)(ws + off); off += (size_t)(N_NODES + 1) * 4;
    unsigned short* perm = (unsigned short*)(ws + off); off += (size_t)E_EDGES * 2;
    off = (off + 255) & ~(size_t)255;
    int* lexcl  = (int*)(ws + off); off += (size_t)N_NODES * 4;
    int* btot   = (int*)(ws + off); off += 64 * 4;
    int* bbase  = (int*)(ws + off); off += 64 * 4;
    (void)ws_size; (void)in_sizes; (void)n_in; (void)out_size;

    const int NB = (N_NODES + 1023) / 1024;

    // ---- CSR build ----
    (void)hipMemsetAsync(deg, 0, (size_t)(N_NODES + 1) * 4, stream);
    hist_deg<<<(E_EDGES + 255) / 256, 256, 0, stream>>>(dst, deg);
    scan1<<<NB, 1024, 0, stream>>>(deg, lexcl, btot);
    scan2<<<1, 64, 0, stream>>>(btot, bbase, NB);
    scan3<<<(N_NODES + 255) / 256, 256, 0, stream>>>(lexcl, bbase, rowptr, cursor);
    fill_csr<<<(E_EDGES + 255) / 256, 256, 0, stream>>>(src, dst, cursor, perm);

    // ---- Weight pre-split ----
    prep_all<<<70, 256, 0, stream>>>(W1, W2, W3, W4, Wl,
                                     W1h, W1l, W2h, W2l, W3h, W3l,
                                     W4h, W4l, Wlh, Wll);

    const int aggBlocks = (N_NODES * 64 + 255) / 256;   // one wave per node
    const int rc2 = (N_NODES + 127) / 128;              // 391 (RPW=2)
    const int rc1 = (N_NODES + 63) / 64;                // 782 (RPW=1)

    // ---- Layer 1 (R11 config) ----
    gather_agg<<<aggBlocks, 256, 0, stream>>>(x, rowptr, perm, hF);
    gemm_split<128, 128, 128, true, 2, 2><<<rc2 * 2, 256, 0, stream>>>(hF, W1h, W1l, b1, h1);
    gemm_split<128, 128, 128, true, 2, 2><<<rc2 * 2, 256, 0, stream>>>(h1, W2h, W2l, b2, h1b);

    // ---- Layer 2 (CSPLIT=4: R12-measured occupancy win on the big GEMMs) ----
    gather_agg<<<aggBlocks, 256, 0, stream>>>(h1b, rowptr, perm, hF2);
    gemm_split<128, 256, 256, true, 4, 2><<<rc2 * 4, 256, 0, stream>>>(hF2, W3h, W3l, b3, h2);
    gemm_split<256, 256, 256, true, 4, 2><<<rc2 * 4, 256, 0, stream>>>(h2, W4h, W4l, b4, h2b);

    // ---- Final linear (R11 config) ----
    gemm_split<256, 48, 40, false, 1, 1><<<rc1, 256, 0, stream>>>(h2b, Wlh, Wll, bl, out);
}